// Round 6
// baseline (606.565 us; speedup 1.0000x reference)
//
#include <hip/hip_runtime.h>
#include <hip/hip_bf16.h>

typedef __attribute__((ext_vector_type(8))) __bf16 bf16x8;
typedef __attribute__((ext_vector_type(4))) float f32x4;

__device__ __forceinline__ void gload_lds16(const void* g, void* lds) {
    __builtin_amdgcn_global_load_lds(
        (const __attribute__((address_space(1))) void*)g,
        (__attribute__((address_space(3))) void*)lds, 16, 0, 0);
}

// ---------------------------------------------------------------------------
// int5 block-64 MSE quant-dequant -> bf16 (per-scale reciprocal)
// ---------------------------------------------------------------------------
__global__ __launch_bounds__(256) void quant_bf16_kernel(
    const float* __restrict__ w, __hip_bfloat16* __restrict__ wq, int nblk)
{
#pragma clang fp contract(off)
    int b = blockIdx.x * 256 + threadIdx.x;
    if (b >= nblk) return;
    const float4* src = (const float4*)(w + (size_t)b * 64);
    float v[64];
#pragma unroll
    for (int i = 0; i < 16; ++i) {
        float4 t = src[i];
        v[i*4+0] = t.x; v[i*4+1] = t.y; v[i*4+2] = t.z; v[i*4+3] = t.w;
    }
    float amax = 0.0f;
#pragma unroll
    for (int i = 0; i < 64; ++i) amax = fmaxf(amax, fabsf(v[i]));
    float base = fmaxf(amax, 1e-8f) / 15.0f;

    float best_err = __builtin_inff();
    float best_scale = base, best_rs = 0.0f;
    for (int k = 0; k < 16; ++k) {
        double sd = (k == 15) ? 1.0 : ((double)k * (0.6 / 15.0) + 0.4);
        float scale = base * (float)sd;
        float rs = 1.0f / scale;
        float err = 0.0f;
#pragma unroll
        for (int i = 0; i < 64; ++i) {
            float q = rintf(v[i] * rs);
            q = fminf(fmaxf(q, -15.0f), 15.0f);
            float d = q * scale - v[i];
            err = err + d * d;
        }
        if (err < best_err) { best_err = err; best_scale = scale; best_rs = rs; }
    }
    __hip_bfloat16* dst = wq + (size_t)b * 64;
#pragma unroll
    for (int i = 0; i < 64; ++i) {
        float q = rintf(v[i] * best_rs);
        q = fminf(fmaxf(q, -15.0f), 15.0f);
        dst[i] = __float2bfloat16(q * best_scale);
    }
}

__global__ __launch_bounds__(256) void f32_to_bf16_kernel(
    const float* __restrict__ in, __hip_bfloat16* __restrict__ out, int n8)
{
    int i = blockIdx.x * 256 + threadIdx.x;
    if (i >= n8) return;
    const float4* p = (const float4*)(in + (size_t)i * 8);
    float4 a = p[0], b = p[1];
    alignas(16) __hip_bfloat16 r[8];
    r[0] = __float2bfloat16(a.x); r[1] = __float2bfloat16(a.y);
    r[2] = __float2bfloat16(a.z); r[3] = __float2bfloat16(a.w);
    r[4] = __float2bfloat16(b.x); r[5] = __float2bfloat16(b.y);
    r[6] = __float2bfloat16(b.z); r[7] = __float2bfloat16(b.w);
    *(uint4*)(out + (size_t)i * 8) = *(const uint4*)r;
}

// ---------------------------------------------------------------------------
// 256x256 tile, BK=64, 8 waves (2Mx4N). ONE barrier per K-tile.
// Per tile t (buf cur = t&1):
//   1. issue 8 gloads staging tile t+1 -> buf[nxt] (pinned at tile start)
//   2. LDB8 + A-frag reads from buf[cur]; 4 window-equivalents of 16 MFMAs
//      with in-place A-subtile reloads (no intra-tile barriers -> waves skew,
//      one wave's ds_read overlaps sibling wave's MFMA on the same SIMD)
//   3. vmcnt(0)  (stagings issued ~4 windows earlier -> latency covered)
//   4. s_barrier
// Ledger: RAW -- buf[cur] was staged during tile t-1 and every wave did
// vmcnt(0) before the barrier ending t-1, so all 8 waves' slices landed.
// WAR -- stagings into buf[nxt] overwrite tile t-1 data whose readers all
// finished before that same barrier.
// LDS swizzle: phys = logical ^ ((row&7)<<4); inverse-swizzled global srcs.
// ---------------------------------------------------------------------------
#define LDA2(d, base, s) { \
    d[0] = *(const bf16x8*)(smem + (base) + aB + (s)*2048u + cb0); \
    d[1] = *(const bf16x8*)(smem + (base) + aB + (s)*2048u + cb1); }

#define LDB8(base) { \
    bf[0][0] = *(const bf16x8*)(smem + (base) + bB + 0u    + cb0); \
    bf[0][1] = *(const bf16x8*)(smem + (base) + bB + 0u    + cb1); \
    bf[1][0] = *(const bf16x8*)(smem + (base) + bB + 2048u + cb0); \
    bf[1][1] = *(const bf16x8*)(smem + (base) + bB + 2048u + cb1); \
    bf[2][0] = *(const bf16x8*)(smem + (base) + bB + 4096u + cb0); \
    bf[2][1] = *(const bf16x8*)(smem + (base) + bB + 4096u + cb1); \
    bf[3][0] = *(const bf16x8*)(smem + (base) + bB + 6144u + cb0); \
    bf[3][1] = *(const bf16x8*)(smem + (base) + bB + 6144u + cb1); }

#define MF8(q, a2) { \
    acc[q][0] = __builtin_amdgcn_mfma_f32_16x16x32_bf16(a2[0], bf[0][0], acc[q][0],0,0,0); \
    acc[q][0] = __builtin_amdgcn_mfma_f32_16x16x32_bf16(a2[1], bf[0][1], acc[q][0],0,0,0); \
    acc[q][1] = __builtin_amdgcn_mfma_f32_16x16x32_bf16(a2[0], bf[1][0], acc[q][1],0,0,0); \
    acc[q][1] = __builtin_amdgcn_mfma_f32_16x16x32_bf16(a2[1], bf[1][1], acc[q][1],0,0,0); \
    acc[q][2] = __builtin_amdgcn_mfma_f32_16x16x32_bf16(a2[0], bf[2][0], acc[q][2],0,0,0); \
    acc[q][2] = __builtin_amdgcn_mfma_f32_16x16x32_bf16(a2[1], bf[2][1], acc[q][2],0,0,0); \
    acc[q][3] = __builtin_amdgcn_mfma_f32_16x16x32_bf16(a2[0], bf[3][0], acc[q][3],0,0,0); \
    acc[q][3] = __builtin_amdgcn_mfma_f32_16x16x32_bf16(a2[1], bf[3][1], acc[q][3],0,0,0); }

#define STAGE(base, eoff, ldsOff) \
    gload_lds16((base) + (size_t)((eoff) + voff), smem + (ldsOff) + wOff)

#define BARRIER() { __builtin_amdgcn_sched_barrier(0); \
    __builtin_amdgcn_s_barrier(); __builtin_amdgcn_sched_barrier(0); }

template <int EPI>  // 0: C=bf16(relu(acc)^2), 1: C=f32 acc
__global__ __launch_bounds__(512, 1) void gemm256_kernel(
    const __hip_bfloat16* __restrict__ A,   // M x K
    const __hip_bfloat16* __restrict__ B,   // N x K
    void* __restrict__ Cout, int M, int N, int K)
{
    extern __shared__ char smem[];

    const int t    = threadIdx.x;
    const int lane = t & 63;
    const int w    = t >> 6;
    const int wr   = w >> 2;
    const int wc   = w & 3;
    const int lo   = lane & 15;
    const int hi   = lane >> 4;
    const uint wOff = (uint)w * 1024u;

    const int cpx = gridDim.x >> 3;
    int bid = blockIdx.x;
    bid = (bid & 7) * cpx + (bid >> 3);
    const int nN = N >> 8;
    const int bm = bid / nN;
    const int bn = bid % nN;
    const int rowBase = bm << 8;
    const int colBase = bn << 8;

    // uniform bases + single per-thread staging offset (inverse-swizzled)
    const __hip_bfloat16* uA = A + (size_t)rowBase * (size_t)K;
    const __hip_bfloat16* uB = B + (size_t)colBase * (size_t)K;
    uint o0 = (uint)t * 16u;
    uint p0 = o0 ^ (((o0 >> 7) & 7u) << 4);
    const uint voff = (p0 >> 7) * (uint)K + ((p0 & 127u) >> 1);
    const uint K64 = (uint)K * 64u;      // 64 rows stride (elements)

    // LDS read addressing (swizzled)
    const uint sw  = (uint)(lo & 7) << 4;
    const uint aB  = (uint)wr * 16384u + (uint)lo * 128u;
    const uint bB  = 32768u + (uint)(wc >> 1) * 16384u
                   + ((uint)(wc & 1) * 64u + (uint)lo) * 128u;
    const uint cb0 = ((uint)hi * 16u) ^ sw;
    const uint cb1 = (64u + (uint)hi * 16u) ^ sw;

    f32x4 acc[8][4] = {};
    bf16x8 aC0[2], aC1[2], bf[4][2];

    // ---- prologue: tile0 -> buf0 ----
    STAGE(uA, 0u,     0u);      STAGE(uA, K64,    8192u);
    STAGE(uA, 2u*K64, 16384u);  STAGE(uA, 3u*K64, 24576u);
    STAGE(uB, 0u,     32768u);  STAGE(uB, K64,    40960u);
    STAGE(uB, 2u*K64, 49152u);  STAGE(uB, 3u*K64, 57344u);
    asm volatile("s_waitcnt vmcnt(0)" ::: "memory");
    BARRIER();

    const int NT = K >> 6;
    for (int tt = 0; tt < NT; ++tt) {
        const uint bufOff = (uint)(tt & 1) * 65536u;
        const uint nxtOff = bufOff ^ 65536u;
        const bool pf = (tt + 1 < NT);
        const uint kN = ((uint)(tt + 1)) << 6;

        if (pf) {
            STAGE(uA, kN,          nxtOff + 0u);
            STAGE(uA, kN + K64,    nxtOff + 8192u);
            STAGE(uA, kN + 2u*K64, nxtOff + 16384u);
            STAGE(uA, kN + 3u*K64, nxtOff + 24576u);
            STAGE(uB, kN,          nxtOff + 32768u);
            STAGE(uB, kN + K64,    nxtOff + 40960u);
            STAGE(uB, kN + 2u*K64, nxtOff + 49152u);
            STAGE(uB, kN + 3u*K64, nxtOff + 57344u);
        }
        __builtin_amdgcn_sched_barrier(0);   // pin stagings at tile start

        LDB8(bufOff);
        LDA2(aC0, bufOff, 0u); LDA2(aC1, bufOff, 1u);

        __builtin_amdgcn_s_setprio(1);
        MF8(0, aC0); LDA2(aC0, bufOff, 2u);
        MF8(1, aC1); LDA2(aC1, bufOff, 3u);
        __builtin_amdgcn_s_setprio(0);

        __builtin_amdgcn_s_setprio(1);
        MF8(2, aC0); LDA2(aC0, bufOff, 4u);
        MF8(3, aC1); LDA2(aC1, bufOff, 5u);
        __builtin_amdgcn_s_setprio(0);

        __builtin_amdgcn_s_setprio(1);
        MF8(4, aC0); LDA2(aC0, bufOff, 6u);
        MF8(5, aC1); LDA2(aC1, bufOff, 7u);
        __builtin_amdgcn_s_setprio(0);

        __builtin_amdgcn_s_setprio(1);
        MF8(6, aC0);
        MF8(7, aC1);
        __builtin_amdgcn_s_setprio(0);

        if (pf) asm volatile("s_waitcnt vmcnt(0)" ::: "memory");
        BARRIER();
    }

    // ---- epilogue: C/D layout col=lane&15, row=(lane>>4)*4+r ----
    if (EPI == 0) {
        __hip_bfloat16* Cb = (__hip_bfloat16*)Cout;
#pragma unroll
        for (int i = 0; i < 8; ++i)
#pragma unroll
            for (int j = 0; j < 4; ++j)
#pragma unroll
                for (int r = 0; r < 4; ++r) {
                    size_t row = rowBase + wr*128 + i*16 + hi*4 + r;
                    size_t col = colBase + wc*64 + j*16 + lo;
                    float v = fmaxf(acc[i][j][r], 0.0f);
                    Cb[row * N + col] = __float2bfloat16(v * v);
                }
    } else {
        float* Cf = (float*)Cout;
#pragma unroll
        for (int i = 0; i < 8; ++i)
#pragma unroll
            for (int j = 0; j < 4; ++j)
#pragma unroll
                for (int r = 0; r < 4; ++r) {
                    size_t row = rowBase + wr*128 + i*16 + hi*4 + r;
                    size_t col = colBase + wc*64 + j*16 + lo;
                    Cf[row * N + col] = acc[i][j][r];
                }
    }
}

// ---------------------------------------------------------------------------
extern "C" void kernel_launch(void* const* d_in, const int* in_sizes, int n_in,
                              void* d_out, int out_size, void* d_ws, size_t ws_size,
                              hipStream_t stream) {
    const float* x      = (const float*)d_in[0];  // 8192 x 2048
    const float* w_fc   = (const float*)d_in[1];  // 8192 x 2048
    const float* w_proj = (const float*)d_in[2];  // 2048 x 8192
    float* out = (float*)d_out;                   // 8192 x 2048

    const int DIM = 2048, HID = 8192, M = 8192;

    char* ws = (char*)d_ws;
    __hip_bfloat16* Xb  = (__hip_bfloat16*)ws;
    __hip_bfloat16* Wfc = (__hip_bfloat16*)(ws + (size_t)M * DIM * 2);
    __hip_bfloat16* Wpj = (__hip_bfloat16*)(ws + (size_t)(M * DIM + (size_t)HID * DIM) * 2);
    __hip_bfloat16* H2  = (__hip_bfloat16*)(ws + (size_t)(M * DIM + 2 * (size_t)HID * DIM) * 2);

    (void)hipFuncSetAttribute((const void*)gemm256_kernel<0>,
                              hipFuncAttributeMaxDynamicSharedMemorySize, 131072);
    (void)hipFuncSetAttribute((const void*)gemm256_kernel<1>,
                              hipFuncAttributeMaxDynamicSharedMemorySize, 131072);

    int nblk = HID * DIM / 64;
    quant_bf16_kernel<<<nblk / 256, 256, 0, stream>>>(w_fc, Wfc, nblk);
    quant_bf16_kernel<<<nblk / 256, 256, 0, stream>>>(w_proj, Wpj, nblk);

    int n8 = M * DIM / 8;
    f32_to_bf16_kernel<<<n8 / 256, 256, 0, stream>>>(x, Xb, n8);

    // H2 = bf16( relu(X @ Wfc^T)^2 )  [8192 x 8192]
    gemm256_kernel<0><<<(M/256)*(HID/256), 512, 131072, stream>>>(
        Xb, Wfc, (void*)H2, M, HID, DIM);

    // out = H2 @ Wpj^T  [8192 x 2048] f32
    gemm256_kernel<1><<<(M/256)*(DIM/256), 512, 131072, stream>>>(
        H2, Wpj, (void*)out, M, DIM, HID);
}